// Round 19
// baseline (383.148 us; speedup 1.0000x reference)
//
#include <hip/hip_runtime.h>

#define MAXDEG 64
#define BINSHIFT 8
#define CAP 5120         // per-bin capacity; mean 4092, +16 sigma
#define CHUNK 4096       // edges per bin_edges block

typedef __bf16 bf16x8 __attribute__((ext_vector_type(8)));
typedef float f32x4 __attribute__((ext_vector_type(4)));

__device__ inline ushort f2bf(float f) {
    unsigned u = __builtin_bit_cast(unsigned, f);
    return (ushort)((u + 0x7fffu + ((u >> 16) & 1u)) >> 16);
}
__device__ inline float bf2f(ushort h) {
    unsigned u = ((unsigned)h) << 16;
    return __builtin_bit_cast(float, u);
}

// split two float4 (8 contiguous f32) into hi/lo bf16 fragments
__device__ inline void split8r(float4 v0, float4 v1, bf16x8& hi, bf16x8& lo) {
    float f[8] = {v0.x, v0.y, v0.z, v0.w, v1.x, v1.y, v1.z, v1.w};
    #pragma unroll
    for (int j = 0; j < 8; ++j) {
        __bf16 h = (__bf16)f[j];
        hi[j] = h;
        lo[j] = (__bf16)(f[j] - (float)h);
    }
}

// ---------------------------------------------------------------------------
// bin_and_prep: fused independent front-end work.
// Blocks [0, nbe): edge binning (LDS histogram -> range reservation -> runs).
// Blocks [nbe, ...): xtobf, 5x weight transpose+split, init_logits, bcat.
// ---------------------------------------------------------------------------
__global__ __launch_bounds__(256) void bin_and_prep(
    const int* __restrict__ src, const int* __restrict__ dst,
    int* __restrict__ bincnt, uint2* __restrict__ binbuf, int E, int nbins, int nbe,
    const float* __restrict__ x, ushort* __restrict__ xb, int n4, int nxb,
    const float* __restrict__ Wl1, ushort* __restrict__ wl1h, ushort* __restrict__ wl1l,
    const float* __restrict__ Wr1, ushort* __restrict__ wr1h, ushort* __restrict__ wr1l,
    const float* __restrict__ Wl2, const float* __restrict__ Wr2,
    ushort* __restrict__ w2h, ushort* __restrict__ w2l,
    const float* __restrict__ Wc1, ushort* __restrict__ wc1h, ushort* __restrict__ wc1l,
    const float* __restrict__ b2, float* __restrict__ bcat,
    const float* __restrict__ bc2, float* __restrict__ logits, int N, int nlb)
{
    const int t = threadIdx.x;
    if (blockIdx.x < (unsigned)nbe) {
        // ---- edge binning ----
        __shared__ int hist[512];
        __shared__ int base[512];
        hist[t] = 0;
        hist[t + 256] = 0;
        __syncthreads();

        const int e0 = blockIdx.x * CHUNK;
        int s[16], d[16], sl[16];
        #pragma unroll
        for (int j = 0; j < 16; ++j) {
            int e = e0 + j * 256 + t;
            if (e < E) {
                s[j]  = src[e];
                d[j]  = dst[e];
                sl[j] = atomicAdd(&hist[d[j] >> BINSHIFT], 1);
            } else {
                d[j] = -1;
            }
        }
        __syncthreads();
        for (int b = t; b < nbins; b += 256)
            if (hist[b] > 0) base[b] = atomicAdd(&bincnt[b], hist[b]);
        __syncthreads();
        #pragma unroll
        for (int j = 0; j < 16; ++j) {
            if (d[j] >= 0) {
                int b = d[j] >> BINSHIFT;
                int pos = base[b] + sl[j];
                if (pos < CAP)
                    binbuf[(size_t)b * CAP + pos] = make_uint2((unsigned)s[j], (unsigned)d[j]);
            }
        }
        return;
    }
    // ---- prep ----
    int bid = blockIdx.x - nbe;
    if (bid < nxb) {
        int i = bid * 256 + t;
        if (i < n4) {
            float4 v = *(const float4*)(x + (size_t)i * 4);
            *(ushort4*)(xb + (size_t)i * 4) =
                make_ushort4(f2bf(v.x), f2bf(v.y), f2bf(v.z), f2bf(v.w));
        }
        return;
    }
    int wb = bid - nxb;
    if (wb < 640) {
        int w = wb >> 7;
        int idx = (wb & 127) * 256 + t;
        const float* W; ushort* Th; ushort* Tl; int K, Nn;
        switch (w) {
            case 0: W = Wl1; Th = wl1h; Tl = wl1l; K = 128; Nn = 256; break;
            case 1: W = Wr1; Th = wr1h; Tl = wr1l; K = 128; Nn = 256; break;
            case 2: W = Wl2; Th = w2h;  Tl = w2l;  K = 256; Nn = 128; break;
            case 3: W = Wr2; Th = w2h + 128 * 256; Tl = w2l + 128 * 256; K = 256; Nn = 128; break;
            default: W = Wc1; Th = wc1h; Tl = wc1l; K = 128; Nn = 256; break;
        }
        int n = idx / K, k = idx % K;
        float v = W[(size_t)k * Nn + n];
        ushort h = f2bf(v);
        Th[idx] = h;
        Tl[idx] = f2bf(v - bf2f(h));
        return;
    }
    wb -= 640;
    if (wb < nlb) {
        int n = wb * 256 + t;
        if (n < N) *(float2*)(logits + (size_t)n * 2) = make_float2(bc2[0], bc2[1]);
        return;
    }
    bcat[t] = t < 128 ? 0.f : b2[t - 128];
}

// ---------------------------------------------------------------------------
// Phase 2: one block per bin (391 blocks -> full machine). deg counting in
// LDS; col writes confined to a 64KB single-XCD window. deg written once.
// ---------------------------------------------------------------------------
__global__ __launch_bounds__(512) void fill_buckets(
    const int* __restrict__ bincnt, const uint2* __restrict__ binbuf,
    int* __restrict__ deg, int* __restrict__ col, int N)
{
    __shared__ int ldeg[256];
    const int b = blockIdx.x;
    const int t = threadIdx.x;
    if (t < 256) ldeg[t] = 0;
    __syncthreads();
    int cnt = bincnt[b];
    cnt = cnt < CAP ? cnt : CAP;
    const uint2* seg = binbuf + (size_t)b * CAP;
    for (int i = t; i < cnt; i += 512) {
        uint2 e = seg[i];
        int slot = atomicAdd(&ldeg[e.y & 255], 1);
        if (slot < MAXDEG) col[(size_t)e.y * MAXDEG + slot] = (int)e.x;
    }
    __syncthreads();
    if (t < 256) {
        int node = (b << BINSHIFT) + t;
        if (node < N) deg[node] = ldeg[t];
    }
}

// ---------------------------------------------------------------------------
// Mean-aggregate (C=128) from bf16 rows -> f32 out. One wave per node;
// lanes split 2-neighbors x 32-lanes x ushort4; 16-neighbor main loop.
// ---------------------------------------------------------------------------
__global__ __launch_bounds__(256) void agg_mean_bf16(
    const ushort* __restrict__ Xb, const int* __restrict__ col,
    const int* __restrict__ deg, float* __restrict__ out, int N)
{
    int gw = (blockIdx.x * 256 + threadIdx.x) >> 6;
    if (gw >= N) return;
    int lane = threadIdx.x & 63;
    int sub = lane >> 5;
    int c4  = (lane & 31) * 4;
    int d = deg[gw];
    int dc = d < MAXDEG ? d : MAXDEG;
    const int* cl = col + (size_t)gw * MAXDEG;
    float a0 = 0.f, a1 = 0.f, a2 = 0.f, a3 = 0.f;
    int i = 0;
    for (; i + 16 <= dc; i += 16) {
        int4 ida = *(const int4*)(cl + i + sub * 4);
        int4 idb = *(const int4*)(cl + i + 8 + sub * 4);
        ushort4 v0 = *(const ushort4*)(Xb + (size_t)ida.x * 128 + c4);
        ushort4 v1 = *(const ushort4*)(Xb + (size_t)ida.y * 128 + c4);
        ushort4 v2 = *(const ushort4*)(Xb + (size_t)ida.z * 128 + c4);
        ushort4 v3 = *(const ushort4*)(Xb + (size_t)ida.w * 128 + c4);
        ushort4 v4 = *(const ushort4*)(Xb + (size_t)idb.x * 128 + c4);
        ushort4 v5 = *(const ushort4*)(Xb + (size_t)idb.y * 128 + c4);
        ushort4 v6 = *(const ushort4*)(Xb + (size_t)idb.z * 128 + c4);
        ushort4 v7 = *(const ushort4*)(Xb + (size_t)idb.w * 128 + c4);
        a0 += ((bf2f(v0.x) + bf2f(v1.x)) + (bf2f(v2.x) + bf2f(v3.x)))
            + ((bf2f(v4.x) + bf2f(v5.x)) + (bf2f(v6.x) + bf2f(v7.x)));
        a1 += ((bf2f(v0.y) + bf2f(v1.y)) + (bf2f(v2.y) + bf2f(v3.y)))
            + ((bf2f(v4.y) + bf2f(v5.y)) + (bf2f(v6.y) + bf2f(v7.y)));
        a2 += ((bf2f(v0.z) + bf2f(v1.z)) + (bf2f(v2.z) + bf2f(v3.z)))
            + ((bf2f(v4.z) + bf2f(v5.z)) + (bf2f(v6.z) + bf2f(v7.z)));
        a3 += ((bf2f(v0.w) + bf2f(v1.w)) + (bf2f(v2.w) + bf2f(v3.w)))
            + ((bf2f(v4.w) + bf2f(v5.w)) + (bf2f(v6.w) + bf2f(v7.w)));
    }
    for (; i + 8 <= dc; i += 8) {
        int4 id = *(const int4*)(cl + i + sub * 4);
        ushort4 v0 = *(const ushort4*)(Xb + (size_t)id.x * 128 + c4);
        ushort4 v1 = *(const ushort4*)(Xb + (size_t)id.y * 128 + c4);
        ushort4 v2 = *(const ushort4*)(Xb + (size_t)id.z * 128 + c4);
        ushort4 v3 = *(const ushort4*)(Xb + (size_t)id.w * 128 + c4);
        a0 += (bf2f(v0.x) + bf2f(v1.x)) + (bf2f(v2.x) + bf2f(v3.x));
        a1 += (bf2f(v0.y) + bf2f(v1.y)) + (bf2f(v2.y) + bf2f(v3.y));
        a2 += (bf2f(v0.z) + bf2f(v1.z)) + (bf2f(v2.z) + bf2f(v3.z));
        a3 += (bf2f(v0.w) + bf2f(v1.w)) + (bf2f(v2.w) + bf2f(v3.w));
    }
    for (; i < dc; i += 2) {
        int j = i + sub;
        if (j < dc) {
            ushort4 v = *(const ushort4*)(Xb + (size_t)cl[j] * 128 + c4);
            a0 += bf2f(v.x); a1 += bf2f(v.y); a2 += bf2f(v.z); a3 += bf2f(v.w);
        }
    }
    a0 += __shfl_xor(a0, 32); a1 += __shfl_xor(a1, 32);
    a2 += __shfl_xor(a2, 32); a3 += __shfl_xor(a3, 32);
    if (sub == 0) {
        float inv = 1.0f / (float)(d > 1 ? d : 1);
        *(float4*)(out + (size_t)gw * 128 + c4) =
            make_float4(a0 * inv, a1 * inv, a2 * inv, a3 * inv);
    }
}

// ---------------------------------------------------------------------------
// agg_finish: h2[n][c] = mean_{s} t2b[s][c] (bf16 gather) + tcat2[n][c]
// ---------------------------------------------------------------------------
__global__ __launch_bounds__(256) void agg_finish(
    const ushort* __restrict__ t2b, const float* __restrict__ tcat2,
    const int* __restrict__ col, const int* __restrict__ deg,
    float* __restrict__ h2, int N)
{
    int gw = (blockIdx.x * 256 + threadIdx.x) >> 6;
    if (gw >= N) return;
    int lane = threadIdx.x & 63;
    int sub = lane >> 5;
    int c4  = (lane & 31) * 4;
    int d = deg[gw];
    int dc = d < MAXDEG ? d : MAXDEG;
    const int* cl = col + (size_t)gw * MAXDEG;
    float a0 = 0.f, a1 = 0.f, a2 = 0.f, a3 = 0.f;
    int i = 0;
    for (; i + 16 <= dc; i += 16) {
        int4 ida = *(const int4*)(cl + i + sub * 4);
        int4 idb = *(const int4*)(cl + i + 8 + sub * 4);
        ushort4 v0 = *(const ushort4*)(t2b + (size_t)ida.x * 128 + c4);
        ushort4 v1 = *(const ushort4*)(t2b + (size_t)ida.y * 128 + c4);
        ushort4 v2 = *(const ushort4*)(t2b + (size_t)ida.z * 128 + c4);
        ushort4 v3 = *(const ushort4*)(t2b + (size_t)ida.w * 128 + c4);
        ushort4 v4 = *(const ushort4*)(t2b + (size_t)idb.x * 128 + c4);
        ushort4 v5 = *(const ushort4*)(t2b + (size_t)idb.y * 128 + c4);
        ushort4 v6 = *(const ushort4*)(t2b + (size_t)idb.z * 128 + c4);
        ushort4 v7 = *(const ushort4*)(t2b + (size_t)idb.w * 128 + c4);
        a0 += ((bf2f(v0.x) + bf2f(v1.x)) + (bf2f(v2.x) + bf2f(v3.x)))
            + ((bf2f(v4.x) + bf2f(v5.x)) + (bf2f(v6.x) + bf2f(v7.x)));
        a1 += ((bf2f(v0.y) + bf2f(v1.y)) + (bf2f(v2.y) + bf2f(v3.y)))
            + ((bf2f(v4.y) + bf2f(v5.y)) + (bf2f(v6.y) + bf2f(v7.y)));
        a2 += ((bf2f(v0.z) + bf2f(v1.z)) + (bf2f(v2.z) + bf2f(v3.z)))
            + ((bf2f(v4.z) + bf2f(v5.z)) + (bf2f(v6.z) + bf2f(v7.z)));
        a3 += ((bf2f(v0.w) + bf2f(v1.w)) + (bf2f(v2.w) + bf2f(v3.w)))
            + ((bf2f(v4.w) + bf2f(v5.w)) + (bf2f(v6.w) + bf2f(v7.w)));
    }
    for (; i + 8 <= dc; i += 8) {
        int4 id = *(const int4*)(cl + i + sub * 4);
        ushort4 v0 = *(const ushort4*)(t2b + (size_t)id.x * 128 + c4);
        ushort4 v1 = *(const ushort4*)(t2b + (size_t)id.y * 128 + c4);
        ushort4 v2 = *(const ushort4*)(t2b + (size_t)id.z * 128 + c4);
        ushort4 v3 = *(const ushort4*)(t2b + (size_t)id.w * 128 + c4);
        a0 += (bf2f(v0.x) + bf2f(v1.x)) + (bf2f(v2.x) + bf2f(v3.x));
        a1 += (bf2f(v0.y) + bf2f(v1.y)) + (bf2f(v2.y) + bf2f(v3.y));
        a2 += (bf2f(v0.z) + bf2f(v1.z)) + (bf2f(v2.z) + bf2f(v3.z));
        a3 += (bf2f(v0.w) + bf2f(v1.w)) + (bf2f(v2.w) + bf2f(v3.w));
    }
    for (; i < dc; i += 2) {
        int j = i + sub;
        if (j < dc) {
            ushort4 v = *(const ushort4*)(t2b + (size_t)cl[j] * 128 + c4);
            a0 += bf2f(v.x); a1 += bf2f(v.y); a2 += bf2f(v.z); a3 += bf2f(v.w);
        }
    }
    a0 += __shfl_xor(a0, 32); a1 += __shfl_xor(a1, 32);
    a2 += __shfl_xor(a2, 32); a3 += __shfl_xor(a3, 32);
    if (sub == 0) {
        float inv = 1.0f / (float)(d > 1 ? d : 1);
        float4 hp = *(const float4*)(tcat2 + (size_t)gw * 128 + c4);
        *(float4*)(h2 + (size_t)gw * 128 + c4) = make_float4(
            a0 * inv + hp.x, a1 * inv + hp.y, a2 * inv + hp.z, a3 * inv + hp.w);
    }
}

// ---------------------------------------------------------------------------
// LDS-staged split-bf16 MFMA GEMM, BM=128, BN=128 (grid.y splits N), BK=32.
// Round-16 geometry + T14 software pipeline: per tile, {write regs->LDS,
// barrier, ISSUE next-tile global loads, compute, barrier} — global-load
// latency hides under the 24-MFMA compute phase (reg double-buffering).
// 512 thr = 8 waves (4M x 2N), wave tile 32x64. LDS 41KB -> 3 blocks/CU.
// 3 passes per k-tile: Ahi*Bhi + Alo*Bhi + Ahi*Blo. Rows padded to 40 ushorts.
// MODE 0: outf[M][256] = act(acc + bias).
// MODE 3: y=0 -> outt2 bf16 [M][128]; y=1 -> outf f32 [M][128] (+bcat bias).
// MODE 1: fused classifier (relu(acc+bias).(sw0|sw1), shfl-reduce, atomicAdd).
// ---------------------------------------------------------------------------
template<int K, int NPH, int MODE>
__global__ __launch_bounds__(512, 4) void gemm_tile(
    const float* __restrict__ A1, const float* __restrict__ A2,
    const ushort* __restrict__ B1hi, const ushort* __restrict__ B1lo,
    const ushort* __restrict__ B2hi, const ushort* __restrict__ B2lo,
    const float* __restrict__ bias, const float* __restrict__ Wc2,
    float* __restrict__ outf, ushort* __restrict__ outt2, int M, int relu)
{
    __shared__ __align__(16) ushort Ah[128 * 40];
    __shared__ __align__(16) ushort Al[128 * 40];
    __shared__ __align__(16) ushort BhS[128 * 40];
    __shared__ __align__(16) ushort BlS[128 * 40];
    __shared__ float sw0[MODE == 1 ? 256 : 4], sw1[MODE == 1 ? 256 : 4];

    const int t = threadIdx.x;
    if constexpr (MODE == 1) {
        if (t < 256) {
            sw0[t] = Wc2[t * 2 + 0];
            sw1[t] = Wc2[t * 2 + 1];
        }
    }

    const int m0 = blockIdx.x * 128;
    const int n0 = blockIdx.y * 128;
    const int l  = t & 63;
    const int wv = t >> 6;
    const int wr = (wv >> 1) * 32;     // wave row base (0..96)
    const int wc = (wv & 1) * 64;      // wave col base (0 or 64)
    const int lr = l & 15;
    const int kb = l >> 4;

    const int sr = t >> 2;             // staging row 0..127
    const int sq = t & 3;              // staging k-quarter (8 elems)

    constexpr int KT = K / 32;         // k-tiles per phase
    constexpr int NT = NPH * KT;       // total tiles

    int rgA = m0 + sr;
    rgA = rgA < M ? rgA : M - 1;
    const size_t aoff = (size_t)rgA * K + sq * 8;
    const size_t boff = (size_t)(n0 + sr) * K + sq * 8;

    f32x4 acc[2][4] = {};

    // fetch registers (tile in flight)
    float4 ar0, ar1;
    uint4  brh, brl;

    // fetch tile 0
    {
        const float* p = A1 + aoff;
        ar0 = *(const float4*)p;
        ar1 = *(const float4*)(p + 4);
        brh = *(const uint4*)(B1hi + boff);
        brl = *(const uint4*)(B1lo + boff);
    }

    for (int tt = 0; tt < NT; ++tt) {
        // write regs -> LDS (split A in-register)
        {
            bf16x8 h0, l0;
            split8r(ar0, ar1, h0, l0);
            int base = sr * 40 + sq * 8;
            *(bf16x8*)&Ah[base] = h0;
            *(bf16x8*)&Al[base] = l0;
            *(uint4*)&BhS[base] = brh;
            *(uint4*)&BlS[base] = brl;
        }
        __syncthreads();
        // issue next tile's global loads (hidden under compute)
        if (tt + 1 < NT) {
            int nt_ = tt + 1;
            int ph  = nt_ / KT;
            int k0  = (nt_ % KT) * 32;
            const float*  A  = (NPH == 2 && ph) ? A2 : A1;
            const ushort* Bh = (NPH == 2 && ph) ? B2hi : B1hi;
            const ushort* Bl = (NPH == 2 && ph) ? B2lo : B1lo;
            const float* p = A + aoff + k0;
            ar0 = *(const float4*)p;
            ar1 = *(const float4*)(p + 4);
            brh = *(const uint4*)(Bh + boff + k0);
            brl = *(const uint4*)(Bl + boff + k0);
        }
        // compute tile tt from LDS
        bf16x8 ah[2], al_[2];
        #pragma unroll
        for (int mi = 0; mi < 2; ++mi) {
            int off = (wr + mi * 16 + lr) * 40 + kb * 8;
            ah[mi]  = *(const bf16x8*)&Ah[off];
            al_[mi] = *(const bf16x8*)&Al[off];
        }
        #pragma unroll
        for (int nj = 0; nj < 4; ++nj) {
            int off = (wc + nj * 16 + lr) * 40 + kb * 8;
            bf16x8 bh = *(const bf16x8*)&BhS[off];
            bf16x8 bl = *(const bf16x8*)&BlS[off];
            #pragma unroll
            for (int mi = 0; mi < 2; ++mi) {
                acc[mi][nj] = __builtin_amdgcn_mfma_f32_16x16x32_bf16(ah[mi],  bh, acc[mi][nj], 0, 0, 0);
                acc[mi][nj] = __builtin_amdgcn_mfma_f32_16x16x32_bf16(al_[mi], bh, acc[mi][nj], 0, 0, 0);
                acc[mi][nj] = __builtin_amdgcn_mfma_f32_16x16x32_bf16(ah[mi],  bl, acc[mi][nj], 0, 0, 0);
            }
        }
        __syncthreads();
    }

    // D map: col = l&15, row = (l>>4)*4 + reg
    if constexpr (MODE != 1) {
        #pragma unroll
        for (int nj = 0; nj < 4; ++nj) {
            int lc   = wc + nj * 16 + lr;     // local col 0..127
            int colg = n0 + lc;               // global col
            float bv = bias[colg];
            #pragma unroll
            for (int mi = 0; mi < 2; ++mi) {
                #pragma unroll
                for (int reg = 0; reg < 4; ++reg) {
                    int rowg = m0 + wr + mi * 16 + kb * 4 + reg;
                    if (rowg >= M) continue;
                    float v = acc[mi][nj][reg] + bv;
                    if (relu) v = fmaxf(v, 0.f);
                    if constexpr (MODE == 0) {
                        outf[(size_t)rowg * 256 + colg] = v;
                    } else {  // MODE 3: y=0 -> t2b bf16; y=1 -> tcat2 f32
                        if (n0 == 0) outt2[(size_t)rowg * 128 + lc] = f2bf(v);
                        else         outf[(size_t)rowg * 128 + lc] = v;
                    }
                }
            }
        }
    } else {
        #pragma unroll
        for (int mi = 0; mi < 2; ++mi) {
            #pragma unroll
            for (int reg = 0; reg < 4; ++reg) {
                float s0 = 0.f, s1 = 0.f;
                #pragma unroll
                for (int nj = 0; nj < 4; ++nj) {
                    int colg = n0 + wc + nj * 16 + lr;
                    float v = fmaxf(acc[mi][nj][reg] + bias[colg], 0.f);
                    s0 += v * sw0[colg];
                    s1 += v * sw1[colg];
                }
                #pragma unroll
                for (int mk = 1; mk < 16; mk <<= 1) {
                    s0 += __shfl_xor(s0, mk);
                    s1 += __shfl_xor(s1, mk);
                }
                int rowg = m0 + wr + mi * 16 + kb * 4 + reg;
                if (lr == 0 && rowg < M) {
                    atomicAdd(&outf[(size_t)rowg * 2 + 0], s0);
                    atomicAdd(&outf[(size_t)rowg * 2 + 1], s1);
                }
            }
        }
    }
}

// ---------------------------------------------------------------------------
extern "C" void kernel_launch(void* const* d_in, const int* in_sizes, int n_in,
                              void* d_out, int out_size, void* d_ws, size_t ws_size,
                              hipStream_t stream)
{
    const float* x   = (const float*)d_in[0];
    const int*   ei  = (const int*)d_in[1];
    const float* Wl1 = (const float*)d_in[2];
    const float* Wr1 = (const float*)d_in[3];
    const float* b1  = (const float*)d_in[4];
    const float* Wl2 = (const float*)d_in[5];
    const float* Wr2 = (const float*)d_in[6];
    const float* b2  = (const float*)d_in[7];
    const float* Wc1 = (const float*)d_in[8];
    const float* bc1 = (const float*)d_in[9];
    const float* Wc2 = (const float*)d_in[10];
    const float* bc2 = (const float*)d_in[11];

    const int N = in_sizes[0] / 128;   // 100000
    const int E = in_sizes[1] / 2;     // 1600000
    const int nbins = (N + (1 << BINSHIFT) - 1) >> BINSHIFT;   // 391

    char* ws = (char*)d_ws;
    size_t off = 0;
    auto alloc = [&](size_t bytes) -> void* {
        void* p = ws + off;
        off += (bytes + 255) & ~(size_t)255;
        return p;
    };
    const size_t NE128 = (size_t)N * 128;
    const size_t NE256 = (size_t)N * 256;

    int*    bincnt = (int*)alloc((size_t)nbins * 4);
    int*    deg  = (int*)alloc((size_t)N * 4);
    int*    colb = (int*)alloc((size_t)N * MAXDEG * 4);
    char*   bufA = (char*)alloc(NE256 * 4);   // binbuf -> a1 f32 -> {t2b bf16, tcat2 f32}
    char*   bufB = (char*)alloc(NE256 * 4);   // xb bf16 -> h1 f32
    ushort* wl1h = (ushort*)alloc(256 * 128 * 2); ushort* wl1l = (ushort*)alloc(256 * 128 * 2);
    ushort* wr1h = (ushort*)alloc(256 * 128 * 2); ushort* wr1l = (ushort*)alloc(256 * 128 * 2);
    ushort* w2h  = (ushort*)alloc(256 * 256 * 2); ushort* w2l  = (ushort*)alloc(256 * 256 * 2);
    ushort* wc1h = (ushort*)alloc(256 * 128 * 2); ushort* wc1l = (ushort*)alloc(256 * 128 * 2);
    float*  bcat = (float*)alloc(256 * 4);

    uint2*  binbuf = (uint2*)bufA;                 // 8MB, dead after fill_buckets
    float*  a1    = (float*)bufA;                  // [N][128] f32 (dead after gemm1)
    ushort* t2b   = (ushort*)bufA;                 // [N][128] bf16 @ [0, NE128*2)
    float*  tcat2 = (float*)(bufA + NE128 * 2);    // [N][128] f32  @ [NE128*2, NE128*6)
    ushort* xb    = (ushort*)bufB;                 // [N][128] bf16 (dead before gemm1 writes h1)
    float*  h1    = (float*)bufB;                  // [N][256] f32

    float* h2     = (float*)d_out;                 // [N][128]  (output 0)
    float* logits = (float*)d_out + NE128;         // [N][2]    (output 1)

    const int gm  = (N + 127) / 128;               // 782
    const int n4  = (int)(NE128 / 4);
    const int nxb = (n4 + 255) / 256;              // 12500
    const int nlb = (N + 255) / 256;               // 391
    const int nbe = (E + CHUNK - 1) / CHUNK;       // 391

    hipMemsetAsync(bincnt, 0, (size_t)nbins * 4, stream);

    // fused: edge binning + all prep (independent work, one launch)
    bin_and_prep<<<dim3(nbe + nxb + 640 + nlb + 1), dim3(256), 0, stream>>>(
        ei, ei + E, bincnt, binbuf, E, nbins, nbe,
        x, xb, n4, nxb,
        Wl1, wl1h, wl1l, Wr1, wr1h, wr1l,
        Wl2, Wr2, w2h, w2l, Wc1, wc1h, wc1l,
        b2, bcat, bc2, logits, N, nlb);

    fill_buckets<<<dim3(nbins), dim3(512), 0, stream>>>(bincnt, binbuf, deg, colb, N);

    // Layer 1: h1 = relu(mean(x)@Wl1 + x@Wr1 + b1)   [N][256] f32
    agg_mean_bf16<<<dim3((N + 3) / 4), dim3(256), 0, stream>>>(xb, colb, deg, a1, N);
    gemm_tile<128, 2, 0><<<dim3(gm, 2), dim3(512), 0, stream>>>(
        a1, x, wl1h, wl1l, wr1h, wr1l, b1, nullptr, h1, nullptr, N, 1);

    // Layer 2 fused: t2b = bf16(h1@Wl2); tcat2 = h1@Wr2 + b2 (f32)
    gemm_tile<256, 1, 3><<<dim3(gm, 2), dim3(512), 0, stream>>>(
        h1, nullptr, w2h, w2l, nullptr, nullptr, bcat, nullptr, tcat2, t2b, N, 0);

    // h2 = mean(t2b) + tcat2  -> d_out
    agg_finish<<<dim3((N + 3) / 4), dim3(256), 0, stream>>>(
        t2b, tcat2, colb, deg, h2, N);

    // Classifier fused: logits += relu(h2@Wc1 + bc1) @ Wc2  (bc2 pre-init)
    gemm_tile<128, 1, 1><<<dim3(gm, 2), dim3(512), 0, stream>>>(
        h2, nullptr, wc1h, wc1l, nullptr, nullptr, bc1, Wc2, logits, nullptr, N, 1);
}

// Round 20
// 376.502 us; speedup vs baseline: 1.0177x; 1.0177x over previous
//
#include <hip/hip_runtime.h>

#define MAXDEG 64
#define BINSHIFT 8
#define CAP 5120         // per-bin capacity; mean 4092, +16 sigma
#define CHUNK 4096       // edges per bin_edges block

typedef __bf16 bf16x8 __attribute__((ext_vector_type(8)));
typedef float f32x4 __attribute__((ext_vector_type(4)));

__device__ inline ushort f2bf(float f) {
    unsigned u = __builtin_bit_cast(unsigned, f);
    return (ushort)((u + 0x7fffu + ((u >> 16) & 1u)) >> 16);
}
__device__ inline float bf2f(ushort h) {
    unsigned u = ((unsigned)h) << 16;
    return __builtin_bit_cast(float, u);
}

// split 8 contiguous f32 into hi/lo bf16 fragments (in-register)
__device__ inline void split8(const float* __restrict__ p, bf16x8& hi, bf16x8& lo) {
    float4 v0 = *(const float4*)p;
    float4 v1 = *(const float4*)(p + 4);
    float f[8] = {v0.x, v0.y, v0.z, v0.w, v1.x, v1.y, v1.z, v1.w};
    #pragma unroll
    for (int j = 0; j < 8; ++j) {
        __bf16 h = (__bf16)f[j];
        hi[j] = h;
        lo[j] = (__bf16)(f[j] - (float)h);
    }
}

// ---------------------------------------------------------------------------
// bin_and_prep: fused independent front-end work.
// Blocks [0, nbe): edge binning (LDS histogram -> range reservation -> runs).
// Blocks [nbe, ...): xtobf, 5x weight transpose+split, init_logits, bcat.
// ---------------------------------------------------------------------------
__global__ __launch_bounds__(256) void bin_and_prep(
    const int* __restrict__ src, const int* __restrict__ dst,
    int* __restrict__ bincnt, uint2* __restrict__ binbuf, int E, int nbins, int nbe,
    const float* __restrict__ x, ushort* __restrict__ xb, int n4, int nxb,
    const float* __restrict__ Wl1, ushort* __restrict__ wl1h, ushort* __restrict__ wl1l,
    const float* __restrict__ Wr1, ushort* __restrict__ wr1h, ushort* __restrict__ wr1l,
    const float* __restrict__ Wl2, const float* __restrict__ Wr2,
    ushort* __restrict__ w2h, ushort* __restrict__ w2l,
    const float* __restrict__ Wc1, ushort* __restrict__ wc1h, ushort* __restrict__ wc1l,
    const float* __restrict__ b2, float* __restrict__ bcat,
    const float* __restrict__ bc2, float* __restrict__ logits, int N, int nlb)
{
    const int t = threadIdx.x;
    if (blockIdx.x < (unsigned)nbe) {
        // ---- edge binning ----
        __shared__ int hist[512];
        __shared__ int base[512];
        hist[t] = 0;
        hist[t + 256] = 0;
        __syncthreads();

        const int e0 = blockIdx.x * CHUNK;
        int s[16], d[16], sl[16];
        #pragma unroll
        for (int j = 0; j < 16; ++j) {
            int e = e0 + j * 256 + t;
            if (e < E) {
                s[j]  = src[e];
                d[j]  = dst[e];
                sl[j] = atomicAdd(&hist[d[j] >> BINSHIFT], 1);
            } else {
                d[j] = -1;
            }
        }
        __syncthreads();
        for (int b = t; b < nbins; b += 256)
            if (hist[b] > 0) base[b] = atomicAdd(&bincnt[b], hist[b]);
        __syncthreads();
        #pragma unroll
        for (int j = 0; j < 16; ++j) {
            if (d[j] >= 0) {
                int b = d[j] >> BINSHIFT;
                int pos = base[b] + sl[j];
                if (pos < CAP)
                    binbuf[(size_t)b * CAP + pos] = make_uint2((unsigned)s[j], (unsigned)d[j]);
            }
        }
        return;
    }
    // ---- prep ----
    int bid = blockIdx.x - nbe;
    if (bid < nxb) {
        int i = bid * 256 + t;
        if (i < n4) {
            float4 v = *(const float4*)(x + (size_t)i * 4);
            *(ushort4*)(xb + (size_t)i * 4) =
                make_ushort4(f2bf(v.x), f2bf(v.y), f2bf(v.z), f2bf(v.w));
        }
        return;
    }
    int wb = bid - nxb;
    if (wb < 640) {
        int w = wb >> 7;
        int idx = (wb & 127) * 256 + t;
        const float* W; ushort* Th; ushort* Tl; int K, Nn;
        switch (w) {
            case 0: W = Wl1; Th = wl1h; Tl = wl1l; K = 128; Nn = 256; break;
            case 1: W = Wr1; Th = wr1h; Tl = wr1l; K = 128; Nn = 256; break;
            case 2: W = Wl2; Th = w2h;  Tl = w2l;  K = 256; Nn = 128; break;
            case 3: W = Wr2; Th = w2h + 128 * 256; Tl = w2l + 128 * 256; K = 256; Nn = 128; break;
            default: W = Wc1; Th = wc1h; Tl = wc1l; K = 128; Nn = 256; break;
        }
        int n = idx / K, k = idx % K;
        float v = W[(size_t)k * Nn + n];
        ushort h = f2bf(v);
        Th[idx] = h;
        Tl[idx] = f2bf(v - bf2f(h));
        return;
    }
    wb -= 640;
    if (wb < nlb) {
        int n = wb * 256 + t;
        if (n < N) *(float2*)(logits + (size_t)n * 2) = make_float2(bc2[0], bc2[1]);
        return;
    }
    bcat[t] = t < 128 ? 0.f : b2[t - 128];
}

// ---------------------------------------------------------------------------
// Phase 2: one block per bin (391 blocks -> full machine). deg counting in
// LDS; col writes confined to a 64KB single-XCD window. deg written once.
// ---------------------------------------------------------------------------
__global__ __launch_bounds__(512) void fill_buckets(
    const int* __restrict__ bincnt, const uint2* __restrict__ binbuf,
    int* __restrict__ deg, int* __restrict__ col, int N)
{
    __shared__ int ldeg[256];
    const int b = blockIdx.x;
    const int t = threadIdx.x;
    if (t < 256) ldeg[t] = 0;
    __syncthreads();
    int cnt = bincnt[b];
    cnt = cnt < CAP ? cnt : CAP;
    const uint2* seg = binbuf + (size_t)b * CAP;
    for (int i = t; i < cnt; i += 512) {
        uint2 e = seg[i];
        int slot = atomicAdd(&ldeg[e.y & 255], 1);
        if (slot < MAXDEG) col[(size_t)e.y * MAXDEG + slot] = (int)e.x;
    }
    __syncthreads();
    if (t < 256) {
        int node = (b << BINSHIFT) + t;
        if (node < N) deg[node] = ldeg[t];
    }
}

// ---------------------------------------------------------------------------
// Mean-aggregate (C=128) from bf16 rows -> f32 out. One wave per node;
// lanes split 2-neighbors x 32-lanes x ushort4; 16-neighbor main loop.
// ---------------------------------------------------------------------------
__global__ __launch_bounds__(256) void agg_mean_bf16(
    const ushort* __restrict__ Xb, const int* __restrict__ col,
    const int* __restrict__ deg, float* __restrict__ out, int N)
{
    int gw = (blockIdx.x * 256 + threadIdx.x) >> 6;
    if (gw >= N) return;
    int lane = threadIdx.x & 63;
    int sub = lane >> 5;
    int c4  = (lane & 31) * 4;
    int d = deg[gw];
    int dc = d < MAXDEG ? d : MAXDEG;
    const int* cl = col + (size_t)gw * MAXDEG;
    float a0 = 0.f, a1 = 0.f, a2 = 0.f, a3 = 0.f;
    int i = 0;
    for (; i + 16 <= dc; i += 16) {
        int4 ida = *(const int4*)(cl + i + sub * 4);
        int4 idb = *(const int4*)(cl + i + 8 + sub * 4);
        ushort4 v0 = *(const ushort4*)(Xb + (size_t)ida.x * 128 + c4);
        ushort4 v1 = *(const ushort4*)(Xb + (size_t)ida.y * 128 + c4);
        ushort4 v2 = *(const ushort4*)(Xb + (size_t)ida.z * 128 + c4);
        ushort4 v3 = *(const ushort4*)(Xb + (size_t)ida.w * 128 + c4);
        ushort4 v4 = *(const ushort4*)(Xb + (size_t)idb.x * 128 + c4);
        ushort4 v5 = *(const ushort4*)(Xb + (size_t)idb.y * 128 + c4);
        ushort4 v6 = *(const ushort4*)(Xb + (size_t)idb.z * 128 + c4);
        ushort4 v7 = *(const ushort4*)(Xb + (size_t)idb.w * 128 + c4);
        a0 += ((bf2f(v0.x) + bf2f(v1.x)) + (bf2f(v2.x) + bf2f(v3.x)))
            + ((bf2f(v4.x) + bf2f(v5.x)) + (bf2f(v6.x) + bf2f(v7.x)));
        a1 += ((bf2f(v0.y) + bf2f(v1.y)) + (bf2f(v2.y) + bf2f(v3.y)))
            + ((bf2f(v4.y) + bf2f(v5.y)) + (bf2f(v6.y) + bf2f(v7.y)));
        a2 += ((bf2f(v0.z) + bf2f(v1.z)) + (bf2f(v2.z) + bf2f(v3.z)))
            + ((bf2f(v4.z) + bf2f(v5.z)) + (bf2f(v6.z) + bf2f(v7.z)));
        a3 += ((bf2f(v0.w) + bf2f(v1.w)) + (bf2f(v2.w) + bf2f(v3.w)))
            + ((bf2f(v4.w) + bf2f(v5.w)) + (bf2f(v6.w) + bf2f(v7.w)));
    }
    for (; i + 8 <= dc; i += 8) {
        int4 id = *(const int4*)(cl + i + sub * 4);
        ushort4 v0 = *(const ushort4*)(Xb + (size_t)id.x * 128 + c4);
        ushort4 v1 = *(const ushort4*)(Xb + (size_t)id.y * 128 + c4);
        ushort4 v2 = *(const ushort4*)(Xb + (size_t)id.z * 128 + c4);
        ushort4 v3 = *(const ushort4*)(Xb + (size_t)id.w * 128 + c4);
        a0 += (bf2f(v0.x) + bf2f(v1.x)) + (bf2f(v2.x) + bf2f(v3.x));
        a1 += (bf2f(v0.y) + bf2f(v1.y)) + (bf2f(v2.y) + bf2f(v3.y));
        a2 += (bf2f(v0.z) + bf2f(v1.z)) + (bf2f(v2.z) + bf2f(v3.z));
        a3 += (bf2f(v0.w) + bf2f(v1.w)) + (bf2f(v2.w) + bf2f(v3.w));
    }
    for (; i < dc; i += 2) {
        int j = i + sub;
        if (j < dc) {
            ushort4 v = *(const ushort4*)(Xb + (size_t)cl[j] * 128 + c4);
            a0 += bf2f(v.x); a1 += bf2f(v.y); a2 += bf2f(v.z); a3 += bf2f(v.w);
        }
    }
    a0 += __shfl_xor(a0, 32); a1 += __shfl_xor(a1, 32);
    a2 += __shfl_xor(a2, 32); a3 += __shfl_xor(a3, 32);
    if (sub == 0) {
        float inv = 1.0f / (float)(d > 1 ? d : 1);
        *(float4*)(out + (size_t)gw * 128 + c4) =
            make_float4(a0 * inv, a1 * inv, a2 * inv, a3 * inv);
    }
}

// ---------------------------------------------------------------------------
// agg_finish: h2[n][c] = mean_{s} t2b[s][c] (bf16 gather) + tcat2[n][c]
// ---------------------------------------------------------------------------
__global__ __launch_bounds__(256) void agg_finish(
    const ushort* __restrict__ t2b, const float* __restrict__ tcat2,
    const int* __restrict__ col, const int* __restrict__ deg,
    float* __restrict__ h2, int N)
{
    int gw = (blockIdx.x * 256 + threadIdx.x) >> 6;
    if (gw >= N) return;
    int lane = threadIdx.x & 63;
    int sub = lane >> 5;
    int c4  = (lane & 31) * 4;
    int d = deg[gw];
    int dc = d < MAXDEG ? d : MAXDEG;
    const int* cl = col + (size_t)gw * MAXDEG;
    float a0 = 0.f, a1 = 0.f, a2 = 0.f, a3 = 0.f;
    int i = 0;
    for (; i + 16 <= dc; i += 16) {
        int4 ida = *(const int4*)(cl + i + sub * 4);
        int4 idb = *(const int4*)(cl + i + 8 + sub * 4);
        ushort4 v0 = *(const ushort4*)(t2b + (size_t)ida.x * 128 + c4);
        ushort4 v1 = *(const ushort4*)(t2b + (size_t)ida.y * 128 + c4);
        ushort4 v2 = *(const ushort4*)(t2b + (size_t)ida.z * 128 + c4);
        ushort4 v3 = *(const ushort4*)(t2b + (size_t)ida.w * 128 + c4);
        ushort4 v4 = *(const ushort4*)(t2b + (size_t)idb.x * 128 + c4);
        ushort4 v5 = *(const ushort4*)(t2b + (size_t)idb.y * 128 + c4);
        ushort4 v6 = *(const ushort4*)(t2b + (size_t)idb.z * 128 + c4);
        ushort4 v7 = *(const ushort4*)(t2b + (size_t)idb.w * 128 + c4);
        a0 += ((bf2f(v0.x) + bf2f(v1.x)) + (bf2f(v2.x) + bf2f(v3.x)))
            + ((bf2f(v4.x) + bf2f(v5.x)) + (bf2f(v6.x) + bf2f(v7.x)));
        a1 += ((bf2f(v0.y) + bf2f(v1.y)) + (bf2f(v2.y) + bf2f(v3.y)))
            + ((bf2f(v4.y) + bf2f(v5.y)) + (bf2f(v6.y) + bf2f(v7.y)));
        a2 += ((bf2f(v0.z) + bf2f(v1.z)) + (bf2f(v2.z) + bf2f(v3.z)))
            + ((bf2f(v4.z) + bf2f(v5.z)) + (bf2f(v6.z) + bf2f(v7.z)));
        a3 += ((bf2f(v0.w) + bf2f(v1.w)) + (bf2f(v2.w) + bf2f(v3.w)))
            + ((bf2f(v4.w) + bf2f(v5.w)) + (bf2f(v6.w) + bf2f(v7.w)));
    }
    for (; i + 8 <= dc; i += 8) {
        int4 id = *(const int4*)(cl + i + sub * 4);
        ushort4 v0 = *(const ushort4*)(t2b + (size_t)id.x * 128 + c4);
        ushort4 v1 = *(const ushort4*)(t2b + (size_t)id.y * 128 + c4);
        ushort4 v2 = *(const ushort4*)(t2b + (size_t)id.z * 128 + c4);
        ushort4 v3 = *(const ushort4*)(t2b + (size_t)id.w * 128 + c4);
        a0 += (bf2f(v0.x) + bf2f(v1.x)) + (bf2f(v2.x) + bf2f(v3.x));
        a1 += (bf2f(v0.y) + bf2f(v1.y)) + (bf2f(v2.y) + bf2f(v3.y));
        a2 += (bf2f(v0.z) + bf2f(v1.z)) + (bf2f(v2.z) + bf2f(v3.z));
        a3 += (bf2f(v0.w) + bf2f(v1.w)) + (bf2f(v2.w) + bf2f(v3.w));
    }
    for (; i < dc; i += 2) {
        int j = i + sub;
        if (j < dc) {
            ushort4 v = *(const ushort4*)(t2b + (size_t)cl[j] * 128 + c4);
            a0 += bf2f(v.x); a1 += bf2f(v.y); a2 += bf2f(v.z); a3 += bf2f(v.w);
        }
    }
    a0 += __shfl_xor(a0, 32); a1 += __shfl_xor(a1, 32);
    a2 += __shfl_xor(a2, 32); a3 += __shfl_xor(a3, 32);
    if (sub == 0) {
        float inv = 1.0f / (float)(d > 1 ? d : 1);
        float4 hp = *(const float4*)(tcat2 + (size_t)gw * 128 + c4);
        *(float4*)(h2 + (size_t)gw * 128 + c4) = make_float4(
            a0 * inv + hp.x, a1 * inv + hp.y, a2 * inv + hp.z, a3 * inv + hp.w);
    }
}

// ---------------------------------------------------------------------------
// LDS-staged split-bf16 MFMA GEMM, BM=128, BN=128 (grid.y splits N), BK=32.
// (round-16/18 configuration — best measured.) 512 thr = 8 waves (4M x 2N),
// wave tile 32x64. LDS 41KB -> 3 blocks/CU. 3 passes per k-tile:
// Ahi*Bhi + Alo*Bhi + Ahi*Blo. Rows padded to 40 ushorts.
// MODE 0: outf[M][256] = act(acc + bias).
// MODE 3: y=0 -> outt2 bf16 [M][128]; y=1 -> outf f32 [M][128] (+bcat bias).
// MODE 1: fused classifier (relu(acc+bias).(sw0|sw1), shfl-reduce, atomicAdd).
// ---------------------------------------------------------------------------
template<int K, int NPH, int MODE>
__global__ __launch_bounds__(512, 4) void gemm_tile(
    const float* __restrict__ A1, const float* __restrict__ A2,
    const ushort* __restrict__ B1hi, const ushort* __restrict__ B1lo,
    const ushort* __restrict__ B2hi, const ushort* __restrict__ B2lo,
    const float* __restrict__ bias, const float* __restrict__ Wc2,
    float* __restrict__ outf, ushort* __restrict__ outt2, int M, int relu)
{
    __shared__ __align__(16) ushort Ah[128 * 40];
    __shared__ __align__(16) ushort Al[128 * 40];
    __shared__ __align__(16) ushort BhS[128 * 40];
    __shared__ __align__(16) ushort BlS[128 * 40];
    __shared__ float sw0[MODE == 1 ? 256 : 4], sw1[MODE == 1 ? 256 : 4];

    const int t = threadIdx.x;
    if constexpr (MODE == 1) {
        if (t < 256) {
            sw0[t] = Wc2[t * 2 + 0];
            sw1[t] = Wc2[t * 2 + 1];
        }
    }

    const int m0 = blockIdx.x * 128;
    const int n0 = blockIdx.y * 128;
    const int l  = t & 63;
    const int wv = t >> 6;
    const int wr = (wv >> 1) * 32;     // wave row base (0..96)
    const int wc = (wv & 1) * 64;      // wave col base (0 or 64)
    const int lr = l & 15;
    const int kb = l >> 4;

    const int sr = t >> 2;             // staging row 0..127
    const int sq = t & 3;              // staging k-quarter (8 elems)

    f32x4 acc[2][4] = {};

    #pragma unroll
    for (int ph = 0; ph < NPH; ++ph) {
        const float*  A  = ph ? A2 : A1;
        const ushort* Bh = ph ? B2hi : B1hi;
        const ushort* Bl = ph ? B2lo : B1lo;
        for (int k0 = 0; k0 < K; k0 += 32) {
            __syncthreads();
            // stage A (f32 -> hi/lo): 128 rows x 32 k, 8 f32 per thread
            {
                int rg = m0 + sr;
                rg = rg < M ? rg : M - 1;
                const float* p = A + (size_t)rg * K + k0 + sq * 8;
                bf16x8 h0, l0;
                split8(p, h0, l0);
                int base = sr * 40 + sq * 8;
                *(bf16x8*)&Ah[base] = h0;
                *(bf16x8*)&Al[base] = l0;
            }
            // stage B (pre-split): 128 rows (n0..n0+127) x 32 k
            {
                const ushort* ph_ = Bh + (size_t)(n0 + sr) * K + k0 + sq * 8;
                const ushort* pl_ = Bl + (size_t)(n0 + sr) * K + k0 + sq * 8;
                int base = sr * 40 + sq * 8;
                *(uint4*)&BhS[base] = *(const uint4*)ph_;
                *(uint4*)&BlS[base] = *(const uint4*)pl_;
            }
            __syncthreads();
            // compute: hoist A frags, loop nj
            bf16x8 ah[2], al_[2];
            #pragma unroll
            for (int mi = 0; mi < 2; ++mi) {
                int off = (wr + mi * 16 + lr) * 40 + kb * 8;
                ah[mi]  = *(const bf16x8*)&Ah[off];
                al_[mi] = *(const bf16x8*)&Al[off];
            }
            #pragma unroll
            for (int nj = 0; nj < 4; ++nj) {
                int off = (wc + nj * 16 + lr) * 40 + kb * 8;
                bf16x8 bh = *(const bf16x8*)&BhS[off];
                bf16x8 bl = *(const bf16x8*)&BlS[off];
                #pragma unroll
                for (int mi = 0; mi < 2; ++mi) {
                    acc[mi][nj] = __builtin_amdgcn_mfma_f32_16x16x32_bf16(ah[mi],  bh, acc[mi][nj], 0, 0, 0);
                    acc[mi][nj] = __builtin_amdgcn_mfma_f32_16x16x32_bf16(al_[mi], bh, acc[mi][nj], 0, 0, 0);
                    acc[mi][nj] = __builtin_amdgcn_mfma_f32_16x16x32_bf16(ah[mi],  bl, acc[mi][nj], 0, 0, 0);
                }
            }
        }
    }

    // D map: col = l&15, row = (l>>4)*4 + reg
    if constexpr (MODE != 1) {
        #pragma unroll
        for (int nj = 0; nj < 4; ++nj) {
            int lc   = wc + nj * 16 + lr;     // local col 0..127
            int colg = n0 + lc;               // global col
            float bv = bias[colg];
            #pragma unroll
            for (int mi = 0; mi < 2; ++mi) {
                #pragma unroll
                for (int reg = 0; reg < 4; ++reg) {
                    int rowg = m0 + wr + mi * 16 + kb * 4 + reg;
                    if (rowg >= M) continue;
                    float v = acc[mi][nj][reg] + bv;
                    if (relu) v = fmaxf(v, 0.f);
                    if constexpr (MODE == 0) {
                        outf[(size_t)rowg * 256 + colg] = v;
                    } else {  // MODE 3: y=0 -> t2b bf16; y=1 -> tcat2 f32
                        if (n0 == 0) outt2[(size_t)rowg * 128 + lc] = f2bf(v);
                        else         outf[(size_t)rowg * 128 + lc] = v;
                    }
                }
            }
        }
    } else {
        #pragma unroll
        for (int mi = 0; mi < 2; ++mi) {
            #pragma unroll
            for (int reg = 0; reg < 4; ++reg) {
                float s0 = 0.f, s1 = 0.f;
                #pragma unroll
                for (int nj = 0; nj < 4; ++nj) {
                    int colg = n0 + wc + nj * 16 + lr;
                    float v = fmaxf(acc[mi][nj][reg] + bias[colg], 0.f);
                    s0 += v * sw0[colg];
                    s1 += v * sw1[colg];
                }
                #pragma unroll
                for (int mk = 1; mk < 16; mk <<= 1) {
                    s0 += __shfl_xor(s0, mk);
                    s1 += __shfl_xor(s1, mk);
                }
                int rowg = m0 + wr + mi * 16 + kb * 4 + reg;
                if (lr == 0 && rowg < M) {
                    atomicAdd(&outf[(size_t)rowg * 2 + 0], s0);
                    atomicAdd(&outf[(size_t)rowg * 2 + 1], s1);
                }
            }
        }
    }
}

// ---------------------------------------------------------------------------
extern "C" void kernel_launch(void* const* d_in, const int* in_sizes, int n_in,
                              void* d_out, int out_size, void* d_ws, size_t ws_size,
                              hipStream_t stream)
{
    const float* x   = (const float*)d_in[0];
    const int*   ei  = (const int*)d_in[1];
    const float* Wl1 = (const float*)d_in[2];
    const float* Wr1 = (const float*)d_in[3];
    const float* b1  = (const float*)d_in[4];
    const float* Wl2 = (const float*)d_in[5];
    const float* Wr2 = (const float*)d_in[6];
    const float* b2  = (const float*)d_in[7];
    const float* Wc1 = (const float*)d_in[8];
    const float* bc1 = (const float*)d_in[9];
    const float* Wc2 = (const float*)d_in[10];
    const float* bc2 = (const float*)d_in[11];

    const int N = in_sizes[0] / 128;   // 100000
    const int E = in_sizes[1] / 2;     // 1600000
    const int nbins = (N + (1 << BINSHIFT) - 1) >> BINSHIFT;   // 391

    char* ws = (char*)d_ws;
    size_t off = 0;
    auto alloc = [&](size_t bytes) -> void* {
        void* p = ws + off;
        off += (bytes + 255) & ~(size_t)255;
        return p;
    };
    const size_t NE128 = (size_t)N * 128;
    const size_t NE256 = (size_t)N * 256;

    int*    bincnt = (int*)alloc((size_t)nbins * 4);
    int*    deg  = (int*)alloc((size_t)N * 4);
    int*    colb = (int*)alloc((size_t)N * MAXDEG * 4);
    char*   bufA = (char*)alloc(NE256 * 4);   // binbuf -> a1 f32 -> {t2b bf16, tcat2 f32}
    char*   bufB = (char*)alloc(NE256 * 4);   // xb bf16 -> h1 f32
    ushort* wl1h = (ushort*)alloc(256 * 128 * 2); ushort* wl1l = (ushort*)alloc(256 * 128 * 2);
    ushort* wr1h = (ushort*)alloc(256 * 128 * 2); ushort* wr1l = (ushort*)alloc(256 * 128 * 2);
    ushort* w2h  = (ushort*)alloc(256 * 256 * 2); ushort* w2l  = (ushort*)alloc(256 * 256 * 2);
    ushort* wc1h = (ushort*)alloc(256 * 128 * 2); ushort* wc1l = (ushort*)alloc(256 * 128 * 2);
    float*  bcat = (float*)alloc(256 * 4);

    uint2*  binbuf = (uint2*)bufA;                 // 8MB, dead after fill_buckets
    float*  a1    = (float*)bufA;                  // [N][128] f32 (dead after gemm1)
    ushort* t2b   = (ushort*)bufA;                 // [N][128] bf16 @ [0, NE128*2)
    float*  tcat2 = (float*)(bufA + NE128 * 2);    // [N][128] f32  @ [NE128*2, NE128*6)
    ushort* xb    = (ushort*)bufB;                 // [N][128] bf16 (dead before gemm1 writes h1)
    float*  h1    = (float*)bufB;                  // [N][256] f32

    float* h2     = (float*)d_out;                 // [N][128]  (output 0)
    float* logits = (float*)d_out + NE128;         // [N][2]    (output 1)

    const int gm  = (N + 127) / 128;               // 782
    const int n4  = (int)(NE128 / 4);
    const int nxb = (n4 + 255) / 256;              // 12500
    const int nlb = (N + 255) / 256;               // 391
    const int nbe = (E + CHUNK - 1) / CHUNK;       // 391

    hipMemsetAsync(bincnt, 0, (size_t)nbins * 4, stream);

    // fused: edge binning + all prep (independent work, one launch)
    bin_and_prep<<<dim3(nbe + nxb + 640 + nlb + 1), dim3(256), 0, stream>>>(
        ei, ei + E, bincnt, binbuf, E, nbins, nbe,
        x, xb, n4, nxb,
        Wl1, wl1h, wl1l, Wr1, wr1h, wr1l,
        Wl2, Wr2, w2h, w2l, Wc1, wc1h, wc1l,
        b2, bcat, bc2, logits, N, nlb);

    fill_buckets<<<dim3(nbins), dim3(512), 0, stream>>>(bincnt, binbuf, deg, colb, N);

    // Layer 1: h1 = relu(mean(x)@Wl1 + x@Wr1 + b1)   [N][256] f32
    agg_mean_bf16<<<dim3((N + 3) / 4), dim3(256), 0, stream>>>(xb, colb, deg, a1, N);
    gemm_tile<128, 2, 0><<<dim3(gm, 2), dim3(512), 0, stream>>>(
        a1, x, wl1h, wl1l, wr1h, wr1l, b1, nullptr, h1, nullptr, N, 1);

    // Layer 2 fused: t2b = bf16(h1@Wl2); tcat2 = h1@Wr2 + b2 (f32)
    gemm_tile<256, 1, 3><<<dim3(gm, 2), dim3(512), 0, stream>>>(
        h1, nullptr, w2h, w2l, nullptr, nullptr, bcat, nullptr, tcat2, t2b, N, 0);

    // h2 = mean(t2b) + tcat2  -> d_out
    agg_finish<<<dim3((N + 3) / 4), dim3(256), 0, stream>>>(
        t2b, tcat2, colb, deg, h2, N);

    // Classifier fused: logits += relu(h2@Wc1 + bc1) @ Wc2  (bc2 pre-init)
    gemm_tile<128, 1, 1><<<dim3(gm, 2), dim3(512), 0, stream>>>(
        h2, nullptr, wc1h, wc1l, nullptr, nullptr, bc1, Wc2, logits, nullptr, N, 1);
}